// Round 4
// baseline (115.989 us; speedup 1.0000x reference)
//
#include <hip/hip_runtime.h>
#include <hip/hip_bf16.h>

// Shapes (fixed by setup_inputs): B=32, L=2048, V=30522, Dw=300, H=768, S=L/P=128
#define B_   32
#define L_   2048
#define V_   30522
#define DW   300
#define H_   768
#define KP   320              // Dw padded to multiple of 32 for MFMA K
#define NT   (H_/16)          // 48 n-tiles
#define KT   (KP/32)          // 10 k-tiles
#define HNT  24               // n-tiles per half-panel (24 KB)
#define VPAD 30528            // V rounded up to multiple of 16 (30528/16/4 = 477 exact blocks)

typedef __attribute__((ext_vector_type(8))) short bf16x8;
typedef __attribute__((ext_vector_type(4))) float f32x4;

// ---------------- K0a: pack W [300][768] fp32 -> Wp bf16, fragment f = kt*NT + n --------------
// Wp[f*64 + lane] = 8 bf16: W[k0+j][col], col = n*16 + (lane&15), k0 = kt*32 + (lane>>4)*8.
// kt-major so each half-panel (24 fragments) is CONTIGUOUS for linear global_load_lds staging.
__global__ void pack_w(const float* __restrict__ W, __hip_bfloat16* __restrict__ Wp) {
    int t = blockIdx.x * 256 + threadIdx.x;           // [0, NT*KT*64)
    if (t >= NT * KT * 64) return;
    int lane = t & 63;
    int f    = t >> 6;
    int n    = f % NT;
    int kt   = f / NT;
    int col  = n * 16 + (lane & 15);
    int k0   = kt * 32 + (lane >> 4) * 8;
    union { __hip_bfloat16 h[8]; int4 v; } u;
    #pragma unroll
    for (int j = 0; j < 8; ++j) {
        int k = k0 + j;
        float w = (k < DW) ? W[(size_t)k * H_ + col] : 0.f;
        u.h[j] = __float2bfloat16(w);
    }
    reinterpret_cast<int4*>(Wp)[t] = u.v;
}

// ---------------- K0b: h1 table [VPAD][KP] bf16 = LN1(emb_table) (one wave per vocab row) -----
__global__ void embed_ln1(const float* __restrict__ emb, const float* __restrict__ g1,
                          const float* __restrict__ b1, __hip_bfloat16* __restrict__ h1) {
    int wave = (blockIdx.x * blockDim.x + threadIdx.x) >> 6;
    int lane = threadIdx.x & 63;
    if (wave >= VPAD) return;
    __hip_bfloat16* dst = h1 + (size_t)wave * KP;
    if (wave >= V_) {                                  // zero pad rows
        for (int k = lane; k < KP; k += 64) dst[k] = __float2bfloat16(0.f);
        return;
    }
    const float* row = emb + (size_t)wave * DW;
    float x[5]; float s = 0.f, ss = 0.f;
    #pragma unroll
    for (int i = 0; i < 5; ++i) {                      // 5*64 = 320 covers KP exactly
        int k = lane + i * 64;
        float v = (k < DW) ? row[k] : 0.f;
        x[i] = v; s += v; ss += v * v;
    }
    #pragma unroll
    for (int m = 32; m >= 1; m >>= 1) { s += __shfl_xor(s, m); ss += __shfl_xor(ss, m); }
    float mu   = s / (float)DW;
    float var  = ss / (float)DW - mu * mu;
    float rstd = rsqrtf(var + 1e-12f);
    #pragma unroll
    for (int i = 0; i < 5; ++i) {
        int k = lane + i * 64;
        float o = (k < DW) ? (g1[k] * ((x[i] - mu) * rstd) + b1[k]) : 0.f;
        dst[k] = __float2bfloat16(o);
    }
}

// ---------------- K1: G[v] = LN2(relu(h1[v] @ W + b)); LDS half-panel dbuf, 2 blocks/CU -------
// C/D layout (m89-verified): col = lane&15, row = (lane>>4)*4 + reg.
#define FRAG_BF16 512                                  // bf16 elems per fragment (64 lanes x 8)

__device__ __forceinline__ void stage_frag(const __hip_bfloat16* __restrict__ Wp,
                                           __hip_bfloat16* dst, int nf, int slot, int lane) {
    // half-panel nf = kt*2 + h; fragment global index = nf*HNT + slot (contiguous in Wp)
    const char* g = (const char*)(Wp + ((size_t)nf * HNT + slot) * FRAG_BF16);
    char* l = (char*)(dst + (size_t)slot * FRAG_BF16);
#if __has_builtin(__builtin_amdgcn_global_load_lds)
    // LDS dest: wave-uniform base (HW adds lane*16); global src per-lane.
    __builtin_amdgcn_global_load_lds(
        (const __attribute__((address_space(1))) void*)(g + lane * 16),
        (__attribute__((address_space(3))) void*)l, 16, 0, 0);
#else
    *(int4*)(l + lane * 16) = *(const int4*)(g + lane * 16);
#endif
}

__global__ void __launch_bounds__(256, 2)
gemm_ln2(const __hip_bfloat16* __restrict__ h1, const __hip_bfloat16* __restrict__ Wp,
         const float* __restrict__ bias, const float* __restrict__ g2,
         const float* __restrict__ b2, __hip_bfloat16* __restrict__ G) {
    __shared__ __hip_bfloat16 sB[2][HNT * FRAG_BF16];  // 2 x 24 KB = 48 KB -> 2 blocks/CU
    int w    = threadIdx.x >> 6;
    int lane = threadIdx.x & 63;
    int wave = blockIdx.x * 4 + w;                     // [0, VPAD/16) exactly, no tail
    size_t row0 = (size_t)wave * 16;
    int r = lane & 15, q = lane >> 4;

    const __hip_bfloat16* arow = h1 + (row0 + r) * (size_t)KP + q * 8;

    f32x4 acc[NT];
    #pragma unroll
    for (int n = 0; n < NT; ++n) acc[n] = (f32x4){0.f, 0.f, 0.f, 0.f};

    // prologue: stage half-panel 0 (wave w stages slots w*6..w*6+5), load A for kt=0
    #pragma unroll
    for (int i = 0; i < 6; ++i) stage_frag(Wp, sB[0], 0, w * 6 + i, lane);
    bf16x8 a_cur = *reinterpret_cast<const bf16x8*>(arow);
    bf16x8 a_nxt = a_cur;
    __syncthreads();                                   // drains vmcnt -> half-panel 0 ready

    #pragma unroll                                     // FULL unroll: h compile-time (rule #20)
    for (int step = 0; step < 2 * KT; ++step) {
        const int kt = step >> 1, h = step & 1;
        if (step + 1 < 2 * KT) {                       // stage next half-panel || compute
            #pragma unroll
            for (int i = 0; i < 6; ++i)
                stage_frag(Wp, sB[(step + 1) & 1], step + 1, w * 6 + i, lane);
        }
        if (h == 0 && kt + 1 < KT)                     // prefetch next kt's A under compute
            a_nxt = *reinterpret_cast<const bf16x8*>(arow + (kt + 1) * 32);
        const bf16x8* Bf = reinterpret_cast<const bf16x8*>(sB[step & 1]) + lane;
        #pragma unroll
        for (int nl = 0; nl < HNT; ++nl) {
            bf16x8 bfr = Bf[nl * 64];                  // contiguous 1KB b128 read, conflict-free
            acc[h * HNT + nl] =
                __builtin_amdgcn_mfma_f32_16x16x32_bf16(a_cur, bfr, acc[h * HNT + nl], 0, 0, 0);
        }
        __syncthreads();                               // staging done + readers drained
        if (h == 1) a_cur = a_nxt;
    }

    // bias + relu + per-row (token) stats; row j of this lane-group = row0 + q*4 + j
    float s[4] = {0.f, 0.f, 0.f, 0.f}, ss[4] = {0.f, 0.f, 0.f, 0.f};
    #pragma unroll
    for (int n = 0; n < NT; ++n) {
        float bn = bias[n * 16 + r];
        #pragma unroll
        for (int j = 0; j < 4; ++j) {
            float v = acc[n][j] + bn;
            v = v > 0.f ? v : 0.f;
            acc[n][j] = v;
            s[j] += v; ss[j] += v * v;
        }
    }
    #pragma unroll
    for (int m = 1; m < 16; m <<= 1) {                 // reduce across the 16 cols (lanes)
        #pragma unroll
        for (int j = 0; j < 4; ++j) { s[j] += __shfl_xor(s[j], m); ss[j] += __shfl_xor(ss[j], m); }
    }
    float mu[4], rstd[4];
    #pragma unroll
    for (int j = 0; j < 4; ++j) {
        mu[j] = s[j] / (float)H_;
        float var = ss[j] / (float)H_ - mu[j] * mu[j];
        rstd[j] = rsqrtf(var + 1e-12f);
    }
    #pragma unroll
    for (int n = 0; n < NT; ++n) {
        int col = n * 16 + r;
        float gg = g2[col], bb = b2[col];
        #pragma unroll
        for (int j = 0; j < 4; ++j) {
            size_t rowg = row0 + q * 4 + j;
            float val = gg * (acc[n][j] - mu[j]) * rstd[j] + bb;
            G[rowg * H_ + col] = __float2bfloat16(val);
        }
    }
}

// ---------------- K1.5: per-batch-row separator positions (general mask handling) -------------
__global__ void sep_scan(const int* __restrict__ sep, int* __restrict__ pos, int* __restrict__ nsep) {
    int b = blockIdx.x;
    const int* row = sep + (size_t)b * L_;
    __shared__ int cnt[256];
    int tid = threadIdx.x;
    int local[8]; int c = 0;
    #pragma unroll
    for (int i = 0; i < 8; ++i) { int v = row[tid * 8 + i]; local[i] = v; c += v; }
    cnt[tid] = c; __syncthreads();
    for (int ofs = 1; ofs < 256; ofs <<= 1) {          // Hillis-Steele inclusive scan
        int v = (tid >= ofs) ? cnt[tid - ofs] : 0;
        __syncthreads();
        cnt[tid] += v;
        __syncthreads();
    }
    int w = cnt[tid] - c;                              // exclusive prefix
    #pragma unroll
    for (int i = 0; i < 8; ++i)
        if (local[i]) { pos[(size_t)b * L_ + w] = tid * 8 + i; ++w; }
    if (tid == 255) nsep[b] = cnt[255];
}

// ---------------- K2: out[b,s,:] = mean_{t in seg(b,s)} G[ids[b,t]] + PE[s] -------------------
__global__ void seg_gather(const int* __restrict__ ids, const int* __restrict__ pos,
                           const int* __restrict__ nsep, const __hip_bfloat16* __restrict__ G,
                           float* __restrict__ out, int S) {
    int blk = blockIdx.x;
    int s = blk % S, b = blk / S;
    int tid = threadIdx.x;                             // 256 threads, 3 cols each
    int ns = nsep[b];
    int lo, hi;
    if (s > ns) { lo = 1; hi = 0; }                    // empty segment
    else {
        lo = (s == 0) ? 0 : pos[(size_t)b * L_ + (s - 1)] + 1;
        hi = (s < ns) ? pos[(size_t)b * L_ + s] - 1 : L_ - 1;   // s==ns: tail after last sep
    }
    int cnt = hi - lo + 1; if (cnt < 0) cnt = 0;
    float a0 = 0.f, a1 = 0.f, a2 = 0.f;
    for (int t = lo; t <= hi; ++t) {
        int v = ids[(size_t)b * L_ + t];
        const __hip_bfloat16* gr = G + (size_t)v * H_;
        a0 += __bfloat162float(gr[tid]);
        a1 += __bfloat162float(gr[tid + 256]);
        a2 += __bfloat162float(gr[tid + 512]);
    }
    float inv = (cnt > 0) ? 1.f / (float)cnt : 0.f;
    float* orow = out + ((size_t)b * S + s) * H_;
    const float cexp = -9.210340371976184f / (float)H_;   // -ln(10000)/H
    float acc[3] = {a0, a1, a2};
    #pragma unroll
    for (int c = 0; c < 3; ++c) {
        int n = tid + c * 256;
        int i = n >> 1;
        float div = expf((float)(2 * i) * cexp);
        float ang = (float)s * div;
        float pe  = (n & 1) ? cosf(ang) : sinf(ang);
        orow[n] = acc[c] * inv + pe;
    }
}

// ---------------- host launcher ----------------
extern "C" void kernel_launch(void* const* d_in, const int* in_sizes, int n_in,
                              void* d_out, int out_size, void* d_ws, size_t ws_size,
                              hipStream_t stream) {
    const int*   ids  = (const int*)d_in[0];
    const int*   sep  = (const int*)d_in[1];
    const float* emb  = (const float*)d_in[3];
    const float* g1   = (const float*)d_in[4];
    const float* b1   = (const float*)d_in[5];
    const float* W    = (const float*)d_in[6];
    const float* bias = (const float*)d_in[7];
    const float* g2   = (const float*)d_in[8];
    const float* b2   = (const float*)d_in[9];
    float* out = (float*)d_out;

    int S = out_size / (B_ * H_);                      // 128

    // workspace layout (all 256B-aligned)
    char* ws = (char*)d_ws;
    __hip_bfloat16* Wp  = (__hip_bfloat16*)(ws);                         // 491,520 B
    __hip_bfloat16* h1  = (__hip_bfloat16*)(ws + 491520);                // 19,537,920 B
    __hip_bfloat16* G   = (__hip_bfloat16*)(ws + 491520 + 19537920);     // 46,891,008 B
    int* pos  = (int*)(ws + 491520 + 19537920 + 46891008);               // 262,144 B
    int* nsep = (int*)(ws + 491520 + 19537920 + 46891008 + 262144);      // 128 B
    (void)ws_size; (void)n_in; (void)in_sizes;

    pack_w   <<<(NT * KT * 64 + 255) / 256, 256, 0, stream>>>(W, Wp);
    embed_ln1<<<VPAD / 4, 256, 0, stream>>>(emb, g1, b1, h1);
    gemm_ln2 <<<VPAD / 16 / 4, 256, 0, stream>>>(h1, Wp, bias, g2, b2, G);
    sep_scan <<<B_, 256, 0, stream>>>(sep, pos, nsep);
    seg_gather<<<B_ * S, 256, 0, stream>>>(ids, pos, nsep, G, out, S);
}

// Round 5
// 99.319 us; speedup vs baseline: 1.1678x; 1.1678x over previous
//
#include <hip/hip_runtime.h>
#include <hip/hip_bf16.h>

// Shapes (fixed by setup_inputs): B=32, L=2048, V=30522, Dw=300, H=768, S=L/P=128
#define B_   32
#define L_   2048
#define V_   30522
#define DW   300
#define H_   768
#define KP   320              // Dw padded to multiple of 32 for MFMA K
#define NT   (H_/16)          // 48 n-tiles
#define KT   (KP/32)          // 10 k-tiles
#define HNT  24               // n-tiles per half-panel (24 KB)
#define VPAD 30528            // V rounded up to multiple of 16 (30528/16/4 = 477 exact blocks)

typedef __attribute__((ext_vector_type(8))) short bf16x8;
typedef __attribute__((ext_vector_type(4))) float f32x4;

// ---------------- K0a: pack W [300][768] fp32 -> Wp bf16, fragment f = kt*NT + n --------------
// Wp[f*64 + lane] = 8 bf16: W[k0+j][col], col = n*16 + (lane&15), k0 = kt*32 + (lane>>4)*8.
// kt-major so each half-panel (24 fragments) is CONTIGUOUS for linear global_load_lds staging.
__global__ void pack_w(const float* __restrict__ W, __hip_bfloat16* __restrict__ Wp) {
    int t = blockIdx.x * 256 + threadIdx.x;           // [0, NT*KT*64)
    if (t >= NT * KT * 64) return;
    int lane = t & 63;
    int f    = t >> 6;
    int n    = f % NT;
    int kt   = f / NT;
    int col  = n * 16 + (lane & 15);
    int k0   = kt * 32 + (lane >> 4) * 8;
    union { __hip_bfloat16 h[8]; int4 v; } u;
    #pragma unroll
    for (int j = 0; j < 8; ++j) {
        int k = k0 + j;
        float w = (k < DW) ? W[(size_t)k * H_ + col] : 0.f;
        u.h[j] = __float2bfloat16(w);
    }
    reinterpret_cast<int4*>(Wp)[t] = u.v;
}

// ---------------- K0b: h1 table [VPAD][KP] bf16 = LN1(emb_table) (one wave per vocab row) -----
__global__ void embed_ln1(const float* __restrict__ emb, const float* __restrict__ g1,
                          const float* __restrict__ b1, __hip_bfloat16* __restrict__ h1) {
    int wave = (blockIdx.x * blockDim.x + threadIdx.x) >> 6;
    int lane = threadIdx.x & 63;
    if (wave >= VPAD) return;
    __hip_bfloat16* dst = h1 + (size_t)wave * KP;
    if (wave >= V_) {                                  // zero pad rows
        for (int k = lane; k < KP; k += 64) dst[k] = __float2bfloat16(0.f);
        return;
    }
    const float* row = emb + (size_t)wave * DW;
    float x[5]; float s = 0.f, ss = 0.f;
    #pragma unroll
    for (int i = 0; i < 5; ++i) {                      // 5*64 = 320 covers KP exactly
        int k = lane + i * 64;
        float v = (k < DW) ? row[k] : 0.f;
        x[i] = v; s += v; ss += v * v;
    }
    #pragma unroll
    for (int m = 32; m >= 1; m >>= 1) { s += __shfl_xor(s, m); ss += __shfl_xor(ss, m); }
    float mu   = s / (float)DW;
    float var  = ss / (float)DW - mu * mu;
    float rstd = rsqrtf(var + 1e-12f);
    #pragma unroll
    for (int i = 0; i < 5; ++i) {
        int k = lane + i * 64;
        float o = (k < DW) ? (g1[k] * ((x[i] - mu) * rstd) + b1[k]) : 0.f;
        dst[k] = __float2bfloat16(o);
    }
}

// ---------------- K1: G[v] = LN2(relu(h1[v] @ W + b)); LDS half-panel dbuf ----------
// C/D layout (m89-verified): col = lane&15, row = (lane>>4)*4 + reg.
// launch_bounds(256,1): compiler allocates ~256 VGPR, NO spill (r3 evidence; (256,2)
// capped regs at 128 and spilled acc — r4 evidence). 2 blocks/CU comes from the HW
// limits naturally: 256 regs -> 8 waves/CU, LDS 2x48KB = 96KB <= 160KB.
#define FRAG_BF16 512                                  // bf16 elems per fragment (64 lanes x 8)

__device__ __forceinline__ void stage_frag(const __hip_bfloat16* __restrict__ Wp,
                                           __hip_bfloat16* dst, int nf, int slot, int lane) {
    // half-panel nf = kt*2 + h; fragment global index = nf*HNT + slot (contiguous in Wp)
    const char* g = (const char*)(Wp + ((size_t)nf * HNT + slot) * FRAG_BF16);
    char* l = (char*)(dst + (size_t)slot * FRAG_BF16);
#if __has_builtin(__builtin_amdgcn_global_load_lds)
    // LDS dest: wave-uniform base (HW adds lane*16); global src per-lane.
    __builtin_amdgcn_global_load_lds(
        (const __attribute__((address_space(1))) void*)(g + lane * 16),
        (__attribute__((address_space(3))) void*)l, 16, 0, 0);
#else
    *(int4*)(l + lane * 16) = *(const int4*)(g + lane * 16);
#endif
}

__global__ void __launch_bounds__(256, 1)
gemm_ln2(const __hip_bfloat16* __restrict__ h1, const __hip_bfloat16* __restrict__ Wp,
         const float* __restrict__ bias, const float* __restrict__ g2,
         const float* __restrict__ b2, __hip_bfloat16* __restrict__ G) {
    __shared__ __hip_bfloat16 sB[2][HNT * FRAG_BF16];  // 2 x 24 KB = 48 KB
    int w    = threadIdx.x >> 6;
    int lane = threadIdx.x & 63;
    int wave = blockIdx.x * 4 + w;                     // [0, VPAD/16) exactly, no tail
    size_t row0 = (size_t)wave * 16;
    int r = lane & 15, q = lane >> 4;

    const __hip_bfloat16* arow = h1 + (row0 + r) * (size_t)KP + q * 8;

    f32x4 acc[NT];
    #pragma unroll
    for (int n = 0; n < NT; ++n) acc[n] = (f32x4){0.f, 0.f, 0.f, 0.f};

    // prologue: stage half-panel 0 (wave w stages slots w*6..w*6+5), load A for kt=0
    #pragma unroll
    for (int i = 0; i < 6; ++i) stage_frag(Wp, sB[0], 0, w * 6 + i, lane);
    bf16x8 a_cur = *reinterpret_cast<const bf16x8*>(arow);
    bf16x8 a_nxt = a_cur;
    __syncthreads();                                   // drains vmcnt -> half-panel 0 ready

    #pragma unroll                                     // FULL unroll: h compile-time (rule #20)
    for (int step = 0; step < 2 * KT; ++step) {
        const int kt = step >> 1, h = step & 1;
        if (step + 1 < 2 * KT) {                       // stage next half-panel || compute
            #pragma unroll
            for (int i = 0; i < 6; ++i)
                stage_frag(Wp, sB[(step + 1) & 1], step + 1, w * 6 + i, lane);
        }
        if (h == 0 && kt + 1 < KT)                     // prefetch next kt's A under compute
            a_nxt = *reinterpret_cast<const bf16x8*>(arow + (kt + 1) * 32);
        const bf16x8* Bf = reinterpret_cast<const bf16x8*>(sB[step & 1]) + lane;
        #pragma unroll
        for (int nl = 0; nl < HNT; ++nl) {
            bf16x8 bfr = Bf[nl * 64];                  // contiguous 1KB b128 read, conflict-free
            acc[h * HNT + nl] =
                __builtin_amdgcn_mfma_f32_16x16x32_bf16(a_cur, bfr, acc[h * HNT + nl], 0, 0, 0);
        }
        __syncthreads();                               // staging done + readers drained
        if (h == 1) a_cur = a_nxt;
    }

    // bias + relu + per-row (token) stats; row j of this lane-group = row0 + q*4 + j
    float s[4] = {0.f, 0.f, 0.f, 0.f}, ss[4] = {0.f, 0.f, 0.f, 0.f};
    #pragma unroll
    for (int n = 0; n < NT; ++n) {
        float bn = bias[n * 16 + r];
        #pragma unroll
        for (int j = 0; j < 4; ++j) {
            float v = acc[n][j] + bn;
            v = v > 0.f ? v : 0.f;
            acc[n][j] = v;
            s[j] += v; ss[j] += v * v;
        }
    }
    #pragma unroll
    for (int m = 1; m < 16; m <<= 1) {                 // reduce across the 16 cols (lanes)
        #pragma unroll
        for (int j = 0; j < 4; ++j) { s[j] += __shfl_xor(s[j], m); ss[j] += __shfl_xor(ss[j], m); }
    }
    float mu[4], rstd[4];
    #pragma unroll
    for (int j = 0; j < 4; ++j) {
        mu[j] = s[j] / (float)H_;
        float var = ss[j] / (float)H_ - mu[j] * mu[j];
        rstd[j] = rsqrtf(var + 1e-12f);
    }
    #pragma unroll
    for (int n = 0; n < NT; ++n) {
        int col = n * 16 + r;
        float gg = g2[col], bb = b2[col];
        #pragma unroll
        for (int j = 0; j < 4; ++j) {
            size_t rowg = row0 + q * 4 + j;
            float val = gg * (acc[n][j] - mu[j]) * rstd[j] + bb;
            G[rowg * H_ + col] = __float2bfloat16(val);
        }
    }
}

// ---------------- K1.5: per-batch-row separator positions (general mask handling) -------------
__global__ void sep_scan(const int* __restrict__ sep, int* __restrict__ pos, int* __restrict__ nsep) {
    int b = blockIdx.x;
    const int* row = sep + (size_t)b * L_;
    __shared__ int cnt[256];
    int tid = threadIdx.x;
    int local[8]; int c = 0;
    #pragma unroll
    for (int i = 0; i < 8; ++i) { int v = row[tid * 8 + i]; local[i] = v; c += v; }
    cnt[tid] = c; __syncthreads();
    for (int ofs = 1; ofs < 256; ofs <<= 1) {          // Hillis-Steele inclusive scan
        int v = (tid >= ofs) ? cnt[tid - ofs] : 0;
        __syncthreads();
        cnt[tid] += v;
        __syncthreads();
    }
    int w = cnt[tid] - c;                              // exclusive prefix
    #pragma unroll
    for (int i = 0; i < 8; ++i)
        if (local[i]) { pos[(size_t)b * L_ + w] = tid * 8 + i; ++w; }
    if (tid == 255) nsep[b] = cnt[255];
}

// ---------------- K2: out[b,s,:] = mean_{t in seg(b,s)} G[ids[b,t]] + PE[s] -------------------
__global__ void seg_gather(const int* __restrict__ ids, const int* __restrict__ pos,
                           const int* __restrict__ nsep, const __hip_bfloat16* __restrict__ G,
                           float* __restrict__ out, int S) {
    int blk = blockIdx.x;
    int s = blk % S, b = blk / S;
    int tid = threadIdx.x;                             // 256 threads, 3 cols each
    int ns = nsep[b];
    int lo, hi;
    if (s > ns) { lo = 1; hi = 0; }                    // empty segment
    else {
        lo = (s == 0) ? 0 : pos[(size_t)b * L_ + (s - 1)] + 1;
        hi = (s < ns) ? pos[(size_t)b * L_ + s] - 1 : L_ - 1;   // s==ns: tail after last sep
    }
    int cnt = hi - lo + 1; if (cnt < 0) cnt = 0;
    float a0 = 0.f, a1 = 0.f, a2 = 0.f;
    for (int t = lo; t <= hi; ++t) {
        int v = ids[(size_t)b * L_ + t];
        const __hip_bfloat16* gr = G + (size_t)v * H_;
        a0 += __bfloat162float(gr[tid]);
        a1 += __bfloat162float(gr[tid + 256]);
        a2 += __bfloat162float(gr[tid + 512]);
    }
    float inv = (cnt > 0) ? 1.f / (float)cnt : 0.f;
    float* orow = out + ((size_t)b * S + s) * H_;
    const float cexp = -9.210340371976184f / (float)H_;   // -ln(10000)/H
    float acc[3] = {a0, a1, a2};
    #pragma unroll
    for (int c = 0; c < 3; ++c) {
        int n = tid + c * 256;
        int i = n >> 1;
        float div = expf((float)(2 * i) * cexp);
        float ang = (float)s * div;
        float pe  = (n & 1) ? cosf(ang) : sinf(ang);
        orow[n] = acc[c] * inv + pe;
    }
}

// ---------------- host launcher ----------------
extern "C" void kernel_launch(void* const* d_in, const int* in_sizes, int n_in,
                              void* d_out, int out_size, void* d_ws, size_t ws_size,
                              hipStream_t stream) {
    const int*   ids  = (const int*)d_in[0];
    const int*   sep  = (const int*)d_in[1];
    const float* emb  = (const float*)d_in[3];
    const float* g1   = (const float*)d_in[4];
    const float* b1   = (const float*)d_in[5];
    const float* W    = (const float*)d_in[6];
    const float* bias = (const float*)d_in[7];
    const float* g2   = (const float*)d_in[8];
    const float* b2   = (const float*)d_in[9];
    float* out = (float*)d_out;

    int S = out_size / (B_ * H_);                      // 128

    // workspace layout (all 256B-aligned)
    char* ws = (char*)d_ws;
    __hip_bfloat16* Wp  = (__hip_bfloat16*)(ws);                         // 491,520 B
    __hip_bfloat16* h1  = (__hip_bfloat16*)(ws + 491520);                // 19,537,920 B
    __hip_bfloat16* G   = (__hip_bfloat16*)(ws + 491520 + 19537920);     // 46,891,008 B
    int* pos  = (int*)(ws + 491520 + 19537920 + 46891008);               // 262,144 B
    int* nsep = (int*)(ws + 491520 + 19537920 + 46891008 + 262144);      // 128 B
    (void)ws_size; (void)n_in; (void)in_sizes;

    pack_w   <<<(NT * KT * 64 + 255) / 256, 256, 0, stream>>>(W, Wp);
    embed_ln1<<<VPAD / 4, 256, 0, stream>>>(emb, g1, b1, h1);
    gemm_ln2 <<<VPAD / 16 / 4, 256, 0, stream>>>(h1, Wp, bias, g2, b2, G);
    sep_scan <<<B_, 256, 0, stream>>>(sep, pos, nsep);
    seg_gather<<<B_ * S, 256, 0, stream>>>(ids, pos, nsep, G, out, S);
}

// Round 6
// 93.333 us; speedup vs baseline: 1.2427x; 1.0641x over previous
//
#include <hip/hip_runtime.h>
#include <hip/hip_bf16.h>

// Shapes (fixed by setup_inputs): B=32, L=2048, V=30522, Dw=300, H=768, S=L/P=128
#define B_   32
#define L_   2048
#define V_   30522
#define DW   300
#define H_   768
#define KP   320              // Dw padded to multiple of 32 for MFMA K
#define NT   (H_/16)          // 48 n-tiles
#define KT   (KP/32)          // 10 k-tiles
#define VPAD 30528            // V rounded up; 30528 = 636 * 48 exactly
#define MB   48               // rows per block (3 m-tiles)
#define NW   12               // n-tiles per wave (4 waves x 12 = 48)

typedef __attribute__((ext_vector_type(8))) short bf16x8;
typedef __attribute__((ext_vector_type(4))) float f32x4;

// ---------------- K0a: pack W [300][768] fp32 -> Wp bf16, fragment f = kt*NT + n --------------
// Wp[f*64 + lane] = 8 bf16: W[k0+j][col], col = n*16 + (lane&15), k0 = kt*32 + (lane>>4)*8.
__global__ void pack_w(const float* __restrict__ W, __hip_bfloat16* __restrict__ Wp) {
    int t = blockIdx.x * 256 + threadIdx.x;           // [0, NT*KT*64)
    if (t >= NT * KT * 64) return;
    int lane = t & 63;
    int f    = t >> 6;
    int n    = f % NT;
    int kt   = f / NT;
    int col  = n * 16 + (lane & 15);
    int k0   = kt * 32 + (lane >> 4) * 8;
    union { __hip_bfloat16 h[8]; int4 v; } u;
    #pragma unroll
    for (int j = 0; j < 8; ++j) {
        int k = k0 + j;
        float w = (k < DW) ? W[(size_t)k * H_ + col] : 0.f;
        u.h[j] = __float2bfloat16(w);
    }
    reinterpret_cast<int4*>(Wp)[t] = u.v;
}

// ---------------- K0b: h1 table [VPAD][KP] bf16 = LN1(emb_table) (one wave per vocab row) -----
__global__ void embed_ln1(const float* __restrict__ emb, const float* __restrict__ g1,
                          const float* __restrict__ b1, __hip_bfloat16* __restrict__ h1) {
    int wave = (blockIdx.x * blockDim.x + threadIdx.x) >> 6;
    int lane = threadIdx.x & 63;
    if (wave >= VPAD) return;
    __hip_bfloat16* dst = h1 + (size_t)wave * KP;
    if (wave >= V_) {                                  // zero pad rows
        for (int k = lane; k < KP; k += 64) dst[k] = __float2bfloat16(0.f);
        return;
    }
    const float* row = emb + (size_t)wave * DW;
    float x[5]; float s = 0.f, ss = 0.f;
    #pragma unroll
    for (int i = 0; i < 5; ++i) {                      // 5*64 = 320 covers KP exactly
        int k = lane + i * 64;
        float v = (k < DW) ? row[k] : 0.f;
        x[i] = v; s += v; ss += v * v;
    }
    #pragma unroll
    for (int m = 32; m >= 1; m >>= 1) { s += __shfl_xor(s, m); ss += __shfl_xor(ss, m); }
    float mu   = s / (float)DW;
    float var  = ss / (float)DW - mu * mu;
    float rstd = rsqrtf(var + 1e-12f);
    #pragma unroll
    for (int i = 0; i < 5; ++i) {
        int k = lane + i * 64;
        float o = (k < DW) ? (g1[k] * ((x[i] - mu) * rstd) + b1[k]) : 0.f;
        dst[k] = __float2bfloat16(o);
    }
}

// ---------------- K1: G[v] = LN2(relu(h1[v] @ W + b)) — N-split waves, barrier-free K loop ----
// Block = 48 rows, 4 waves; wave w owns n-tiles [w*12, w*12+12) for ALL 48 rows.
// B-fragment loaded once into regs feeds 3 MFMAs (one per m-tile) — no LDS staging,
// no K-loop barriers, B straight from L2 (Wp = 480 KB, L2-resident, 1KB/load contiguous).
// C/D layout (m89-verified): col = lane&15, row = (lane>>4)*4 + reg.
__global__ void __launch_bounds__(256, 1)
gemm_ln2(const __hip_bfloat16* __restrict__ h1, const __hip_bfloat16* __restrict__ Wp,
         const float* __restrict__ bias, const float* __restrict__ g2,
         const float* __restrict__ b2, __hip_bfloat16* __restrict__ G) {
    __shared__ float sred[2][4][MB];                   // [s|ss][wave][row] — 1.5 KB
    int w    = threadIdx.x >> 6;
    int lane = threadIdx.x & 63;
    int r = lane & 15, q = lane >> 4;
    size_t row0 = (size_t)blockIdx.x * MB;

    f32x4 acc[NW][3];
    #pragma unroll
    for (int nl = 0; nl < NW; ++nl)
        #pragma unroll
        for (int m = 0; m < 3; ++m) acc[nl][m] = (f32x4){0.f, 0.f, 0.f, 0.f};

    const __hip_bfloat16* a0p = h1 + (row0 + r) * (size_t)KP + q * 8;  // m=0 row fragment
    const bf16x8* Bv = reinterpret_cast<const bf16x8*>(Wp) + (size_t)w * NW * 64 + lane;

    #pragma unroll 2
    for (int kt = 0; kt < KT; ++kt) {
        bf16x8 a0 = *reinterpret_cast<const bf16x8*>(a0p + kt * 32);
        bf16x8 a1 = *reinterpret_cast<const bf16x8*>(a0p + 16 * KP + kt * 32);
        bf16x8 a2 = *reinterpret_cast<const bf16x8*>(a0p + 32 * KP + kt * 32);
        const bf16x8* bp = Bv + (size_t)kt * NT * 64;
        #pragma unroll                                 // static acc indices (rule #20)
        for (int nl = 0; nl < NW; ++nl) {
            bf16x8 bv = bp[nl * 64];                   // 1KB contiguous, reused 3x
            acc[nl][0] = __builtin_amdgcn_mfma_f32_16x16x32_bf16(a0, bv, acc[nl][0], 0, 0, 0);
            acc[nl][1] = __builtin_amdgcn_mfma_f32_16x16x32_bf16(a1, bv, acc[nl][1], 0, 0, 0);
            acc[nl][2] = __builtin_amdgcn_mfma_f32_16x16x32_bf16(a2, bv, acc[nl][2], 0, 0, 0);
        }
    }

    // bias + relu + in-wave partial stats (over this wave's 192 cols)
    float s[3][4], ss[3][4];
    #pragma unroll
    for (int m = 0; m < 3; ++m)
        #pragma unroll
        for (int j = 0; j < 4; ++j) { s[m][j] = 0.f; ss[m][j] = 0.f; }
    #pragma unroll
    for (int nl = 0; nl < NW; ++nl) {
        float bn = bias[w * 192 + nl * 16 + r];
        #pragma unroll
        for (int m = 0; m < 3; ++m)
            #pragma unroll
            for (int j = 0; j < 4; ++j) {
                float v = acc[nl][m][j] + bn;
                v = v > 0.f ? v : 0.f;
                acc[nl][m][j] = v;
                s[m][j] += v; ss[m][j] += v * v;
            }
    }
    #pragma unroll
    for (int msk = 1; msk < 16; msk <<= 1)             // reduce across the 16 r-lanes
        #pragma unroll
        for (int m = 0; m < 3; ++m)
            #pragma unroll
            for (int j = 0; j < 4; ++j) {
                s[m][j]  += __shfl_xor(s[m][j],  msk);
                ss[m][j] += __shfl_xor(ss[m][j], msk);
            }
    if (r == 0) {                                      // publish wave partials (12 rows/lane-q)
        #pragma unroll
        for (int m = 0; m < 3; ++m)
            #pragma unroll
            for (int j = 0; j < 4; ++j) {
                int row = m * 16 + q * 4 + j;
                sred[0][w][row] = s[m][j];
                sred[1][w][row] = ss[m][j];
            }
    }
    __syncthreads();

    #pragma unroll
    for (int m = 0; m < 3; ++m) {
        #pragma unroll
        for (int j = 0; j < 4; ++j) {
            int row = m * 16 + q * 4 + j;
            float ts  = sred[0][0][row] + sred[0][1][row] + sred[0][2][row] + sred[0][3][row];
            float tss = sred[1][0][row] + sred[1][1][row] + sred[1][2][row] + sred[1][3][row];
            float mu   = ts / (float)H_;
            float var  = tss / (float)H_ - mu * mu;
            float rstd = rsqrtf(var + 1e-12f);
            s[m][j]  = mu;                             // reuse as mu
            ss[m][j] = rstd;                           // reuse as rstd
        }
    }
    #pragma unroll
    for (int nl = 0; nl < NW; ++nl) {
        int col = w * 192 + nl * 16 + r;
        float gg = g2[col], bb = b2[col];
        #pragma unroll
        for (int m = 0; m < 3; ++m)
            #pragma unroll
            for (int j = 0; j < 4; ++j) {
                size_t rowg = row0 + m * 16 + q * 4 + j;
                float val = gg * (acc[nl][m][j] - s[m][j]) * ss[m][j] + bb;
                G[rowg * H_ + col] = __float2bfloat16(val);
            }
    }
}

// ---------------- K1.5: per-batch-row separator positions (general mask handling) -------------
__global__ void sep_scan(const int* __restrict__ sep, int* __restrict__ pos, int* __restrict__ nsep) {
    int b = blockIdx.x;
    const int* row = sep + (size_t)b * L_;
    __shared__ int cnt[256];
    int tid = threadIdx.x;
    int local[8]; int c = 0;
    #pragma unroll
    for (int i = 0; i < 8; ++i) { int v = row[tid * 8 + i]; local[i] = v; c += v; }
    cnt[tid] = c; __syncthreads();
    for (int ofs = 1; ofs < 256; ofs <<= 1) {          // Hillis-Steele inclusive scan
        int v = (tid >= ofs) ? cnt[tid - ofs] : 0;
        __syncthreads();
        cnt[tid] += v;
        __syncthreads();
    }
    int w = cnt[tid] - c;                              // exclusive prefix
    #pragma unroll
    for (int i = 0; i < 8; ++i)
        if (local[i]) { pos[(size_t)b * L_ + w] = tid * 8 + i; ++w; }
    if (tid == 255) nsep[b] = cnt[255];
}

// ---------------- K2: out[b,s,:] = mean_{t in seg(b,s)} G[ids[b,t]] + PE[s] -------------------
__global__ void seg_gather(const int* __restrict__ ids, const int* __restrict__ pos,
                           const int* __restrict__ nsep, const __hip_bfloat16* __restrict__ G,
                           float* __restrict__ out, int S) {
    int blk = blockIdx.x;
    int s = blk % S, b = blk / S;
    int tid = threadIdx.x;                             // 256 threads, 3 cols each
    int ns = nsep[b];
    int lo, hi;
    if (s > ns) { lo = 1; hi = 0; }                    // empty segment
    else {
        lo = (s == 0) ? 0 : pos[(size_t)b * L_ + (s - 1)] + 1;
        hi = (s < ns) ? pos[(size_t)b * L_ + s] - 1 : L_ - 1;   // s==ns: tail after last sep
    }
    int cnt = hi - lo + 1; if (cnt < 0) cnt = 0;
    float a0 = 0.f, a1 = 0.f, a2 = 0.f;
    for (int t = lo; t <= hi; ++t) {
        int v = ids[(size_t)b * L_ + t];
        const __hip_bfloat16* gr = G + (size_t)v * H_;
        a0 += __bfloat162float(gr[tid]);
        a1 += __bfloat162float(gr[tid + 256]);
        a2 += __bfloat162float(gr[tid + 512]);
    }
    float inv = (cnt > 0) ? 1.f / (float)cnt : 0.f;
    float* orow = out + ((size_t)b * S + s) * H_;
    const float cexp = -9.210340371976184f / (float)H_;   // -ln(10000)/H
    float acc[3] = {a0, a1, a2};
    #pragma unroll
    for (int c = 0; c < 3; ++c) {
        int n = tid + c * 256;
        int i = n >> 1;
        float div = expf((float)(2 * i) * cexp);
        float ang = (float)s * div;
        float pe  = (n & 1) ? cosf(ang) : sinf(ang);
        orow[n] = acc[c] * inv + pe;
    }
}

// ---------------- host launcher ----------------
extern "C" void kernel_launch(void* const* d_in, const int* in_sizes, int n_in,
                              void* d_out, int out_size, void* d_ws, size_t ws_size,
                              hipStream_t stream) {
    const int*   ids  = (const int*)d_in[0];
    const int*   sep  = (const int*)d_in[1];
    const float* emb  = (const float*)d_in[3];
    const float* g1   = (const float*)d_in[4];
    const float* b1   = (const float*)d_in[5];
    const float* W    = (const float*)d_in[6];
    const float* bias = (const float*)d_in[7];
    const float* g2   = (const float*)d_in[8];
    const float* b2   = (const float*)d_in[9];
    float* out = (float*)d_out;

    int S = out_size / (B_ * H_);                      // 128

    // workspace layout (all 256B-aligned)
    char* ws = (char*)d_ws;
    __hip_bfloat16* Wp  = (__hip_bfloat16*)(ws);                         // 491,520 B
    __hip_bfloat16* h1  = (__hip_bfloat16*)(ws + 491520);                // 19,537,920 B
    __hip_bfloat16* G   = (__hip_bfloat16*)(ws + 491520 + 19537920);     // 46,891,008 B
    int* pos  = (int*)(ws + 491520 + 19537920 + 46891008);               // 262,144 B
    int* nsep = (int*)(ws + 491520 + 19537920 + 46891008 + 262144);      // 128 B
    (void)ws_size; (void)n_in; (void)in_sizes;

    pack_w   <<<(NT * KT * 64 + 255) / 256, 256, 0, stream>>>(W, Wp);
    embed_ln1<<<VPAD / 4, 256, 0, stream>>>(emb, g1, b1, h1);
    gemm_ln2 <<<VPAD / MB, 256, 0, stream>>>(h1, Wp, bias, g2, b2, G);
    sep_scan <<<B_, 256, 0, stream>>>(sep, pos, nsep);
    seg_gather<<<B_ * S, 256, 0, stream>>>(ids, pos, nsep, G, out, S);
}